// Round 5
// baseline (357.522 us; speedup 1.0000x reference)
//
#include <hip/hip_runtime.h>

// DiscriminativeLoss: reference output == prediction.sum() exactly.
// Every pixel's label lies in [0, N_INSTANCE_BINS), so the one-hot masks
// sum to 1 everywhere and the einsum collapses to a full sum of
// `prediction`. `target` is mathematically dead — never read it.
//
// R4 evidence: dur 189 us; ~160 us is harness reset traffic (512MB ws
// poison @78us + ~48us input restore), our share ~27us vs ~21us floor.
// R5: (1) 8 loads in flight (MLP), per-accumulator FP add order UNCHANGED
// (absmax has been exactly 0.0 — do not perturb the comparator);
// (2) fuse final reduce via last-block-done (agent-scope atomics,
// explicitly initialized counter — no poison reliance), replicating the
// old stage2's exact add order bit-for-bit.

#define BLOCK 256
#define GRID1 2048   // 256 CUs * 8 blocks/CU

typedef float floatx4 __attribute__((ext_vector_type(4)));

__global__ void init_counter(unsigned* __restrict__ c) { *c = 0u; }

__global__ __launch_bounds__(BLOCK) void sum_fused(
    const float* __restrict__ in, long long n,
    float* __restrict__ partial, unsigned* __restrict__ counter,
    float* __restrict__ out) {
  const long long n4 = n >> 2;  // float4 chunks
  const floatx4* __restrict__ in4 = (const floatx4*)in;
  const long long tid    = (long long)blockIdx.x * BLOCK + threadIdx.x;
  const long long stride = (long long)GRID1 * BLOCK;  // compile-time const

  // 8 nt dwordx4 loads in flight. acc0 consumes strides {0,2,4,6}+8k,
  // acc1 consumes {1,3,5,7}+8k — identical per-acc sequence to the old
  // unroll-2 loop, so the FP result is bit-identical.
  float acc0 = 0.0f, acc1 = 0.0f;
  long long i = tid;
  for (; i + 7 * stride < n4; i += 8 * stride) {
    floatx4 v0 = __builtin_nontemporal_load(&in4[i]);
    floatx4 v1 = __builtin_nontemporal_load(&in4[i + stride]);
    floatx4 v2 = __builtin_nontemporal_load(&in4[i + 2 * stride]);
    floatx4 v3 = __builtin_nontemporal_load(&in4[i + 3 * stride]);
    floatx4 v4 = __builtin_nontemporal_load(&in4[i + 4 * stride]);
    floatx4 v5 = __builtin_nontemporal_load(&in4[i + 5 * stride]);
    floatx4 v6 = __builtin_nontemporal_load(&in4[i + 6 * stride]);
    floatx4 v7 = __builtin_nontemporal_load(&in4[i + 7 * stride]);
    acc0 += (v0.x + v0.y) + (v0.z + v0.w);
    acc1 += (v1.x + v1.y) + (v1.z + v1.w);
    acc0 += (v2.x + v2.y) + (v2.z + v2.w);
    acc1 += (v3.x + v3.y) + (v3.z + v3.w);
    acc0 += (v4.x + v4.y) + (v4.z + v4.w);
    acc1 += (v5.x + v5.y) + (v5.z + v5.w);
    acc0 += (v6.x + v6.y) + (v6.z + v6.w);
    acc1 += (v7.x + v7.y) + (v7.z + v7.w);
  }
  for (; i + stride < n4; i += 2 * stride) {
    floatx4 a = __builtin_nontemporal_load(&in4[i]);
    floatx4 b = __builtin_nontemporal_load(&in4[i + stride]);
    acc0 += (a.x + a.y) + (a.z + a.w);
    acc1 += (b.x + b.y) + (b.z + b.w);
  }
  if (i < n4) {
    floatx4 a = __builtin_nontemporal_load(&in4[i]);
    acc0 += (a.x + a.y) + (a.z + a.w);
  }
  float acc = acc0 + acc1;
  // scalar tail (n % 4 != 0) — empty for this shape, kept for safety
  for (long long j = (n4 << 2) + tid; j < n; j += stride) acc += in[j];

  // wave-64 butterfly reduce (same as before)
  #pragma unroll
  for (int off = 32; off > 0; off >>= 1) acc += __shfl_down(acc, off, 64);

  __shared__ float smem[BLOCK / 64];
  __shared__ int isLast;
  const int lane = threadIdx.x & 63;
  const int wid  = threadIdx.x >> 6;
  if (lane == 0) smem[wid] = acc;
  __syncthreads();
  if (threadIdx.x == 0) {
    float s = 0.0f;
    #pragma unroll
    for (int k = 0; k < BLOCK / 64; ++k) s += smem[k];
    // release-publish this block's partial, then count completion
    __hip_atomic_store(&partial[blockIdx.x], s, __ATOMIC_RELEASE,
                       __HIP_MEMORY_SCOPE_AGENT);
    unsigned old = __hip_atomic_fetch_add(counter, 1u, __ATOMIC_ACQ_REL,
                                          __HIP_MEMORY_SCOPE_AGENT);
    isLast = (old == GRID1 - 1) ? 1 : 0;
  }
  __syncthreads();  // isLast is block-uniform after this

  if (isLast) {
    // exact replica of the old stage2: same order -> bit-identical output
    float a = 0.0f;
    for (int k = threadIdx.x; k < GRID1; k += BLOCK) a += partial[k];
    #pragma unroll
    for (int off = 32; off > 0; off >>= 1) a += __shfl_down(a, off, 64);
    if (lane == 0) smem[wid] = a;
    __syncthreads();  // whole block takes this branch — barrier is safe
    if (threadIdx.x == 0) {
      float s = 0.0f;
      #pragma unroll
      for (int k = 0; k < BLOCK / 64; ++k) s += smem[k];
      out[0] = s;
    }
  }
}

extern "C" void kernel_launch(void* const* d_in, const int* in_sizes, int n_in,
                              void* d_out, int out_size, void* d_ws, size_t ws_size,
                              hipStream_t stream) {
  const float* pred = (const float*)d_in[0];
  // d_in[1] (target, int32) is mathematically dead: one-hot masks sum to 1.
  const long long n = (long long)in_sizes[0];
  float* out = (float*)d_out;

  unsigned* counter = (unsigned*)d_ws;                      // 4 B
  float* partial = (float*)((char*)d_ws + 256);             // separate line

  init_counter<<<1, 1, 0, stream>>>(counter);
  sum_fused<<<GRID1, BLOCK, 0, stream>>>(pred, n, partial, counter, out);
}

// Round 6
// 188.832 us; speedup vs baseline: 1.8933x; 1.8933x over previous
//
#include <hip/hip_runtime.h>

// DiscriminativeLoss: reference output == prediction.sum() exactly.
// One-hot masks over target (all labels in [0,16)) sum to 1 per pixel, so
// the einsum collapses to a full sum of `prediction`; `target` is dead.
//
// R5 post-mortem: fusing the final reduce via agent-scope release/acq_rel
// atomics cost +168us — per-block L2 writeback/invalidate on an 8-XCD
// chip (per-XCD L2 non-coherent) serialized the machine (sum_fused: 203us
// @ 330 GB/s). REVERTED to the two-kernel structure; dispatch boundary
// provides ordering for free. Kept the 8-deep nt-load unroll (FP add
// order per accumulator unchanged -> result bit-identical; absmax=0.0).

#define BLOCK 256
#define GRID1 2048   // 256 CUs * 8 blocks/CU

typedef float floatx4 __attribute__((ext_vector_type(4)));

__global__ __launch_bounds__(BLOCK) void sum_stage1(
    const float* __restrict__ in, long long n, float* __restrict__ partial) {
  const long long n4 = n >> 2;  // float4 chunks
  const floatx4* __restrict__ in4 = (const floatx4*)in;
  const long long tid    = (long long)blockIdx.x * BLOCK + threadIdx.x;
  const long long stride = (long long)GRID1 * BLOCK;  // compile-time const

  // 8 nt dwordx4 loads in flight. acc0 consumes strides {0,2,4,6}+8k,
  // acc1 consumes {1,3,5,7}+8k — identical per-accumulator sequence to
  // the unroll-2 loop, so the FP result is bit-identical.
  float acc0 = 0.0f, acc1 = 0.0f;
  long long i = tid;
  for (; i + 7 * stride < n4; i += 8 * stride) {
    floatx4 v0 = __builtin_nontemporal_load(&in4[i]);
    floatx4 v1 = __builtin_nontemporal_load(&in4[i + stride]);
    floatx4 v2 = __builtin_nontemporal_load(&in4[i + 2 * stride]);
    floatx4 v3 = __builtin_nontemporal_load(&in4[i + 3 * stride]);
    floatx4 v4 = __builtin_nontemporal_load(&in4[i + 4 * stride]);
    floatx4 v5 = __builtin_nontemporal_load(&in4[i + 5 * stride]);
    floatx4 v6 = __builtin_nontemporal_load(&in4[i + 6 * stride]);
    floatx4 v7 = __builtin_nontemporal_load(&in4[i + 7 * stride]);
    acc0 += (v0.x + v0.y) + (v0.z + v0.w);
    acc1 += (v1.x + v1.y) + (v1.z + v1.w);
    acc0 += (v2.x + v2.y) + (v2.z + v2.w);
    acc1 += (v3.x + v3.y) + (v3.z + v3.w);
    acc0 += (v4.x + v4.y) + (v4.z + v4.w);
    acc1 += (v5.x + v5.y) + (v5.z + v5.w);
    acc0 += (v6.x + v6.y) + (v6.z + v6.w);
    acc1 += (v7.x + v7.y) + (v7.z + v7.w);
  }
  for (; i + stride < n4; i += 2 * stride) {
    floatx4 a = __builtin_nontemporal_load(&in4[i]);
    floatx4 b = __builtin_nontemporal_load(&in4[i + stride]);
    acc0 += (a.x + a.y) + (a.z + a.w);
    acc1 += (b.x + b.y) + (b.z + b.w);
  }
  if (i < n4) {
    floatx4 a = __builtin_nontemporal_load(&in4[i]);
    acc0 += (a.x + a.y) + (a.z + a.w);
  }
  float acc = acc0 + acc1;
  // scalar tail (n % 4 != 0) — empty for this shape, kept for safety
  for (long long j = (n4 << 2) + tid; j < n; j += stride) acc += in[j];

  // wave-64 butterfly reduce
  #pragma unroll
  for (int off = 32; off > 0; off >>= 1) acc += __shfl_down(acc, off, 64);

  __shared__ float smem[BLOCK / 64];
  const int lane = threadIdx.x & 63;
  const int wid  = threadIdx.x >> 6;
  if (lane == 0) smem[wid] = acc;
  __syncthreads();
  if (threadIdx.x == 0) {
    float s = 0.0f;
    #pragma unroll
    for (int k = 0; k < BLOCK / 64; ++k) s += smem[k];
    partial[blockIdx.x] = s;
  }
}

__global__ __launch_bounds__(BLOCK) void sum_stage2(
    const float* __restrict__ partial, int n, float* __restrict__ out) {
  float acc = 0.0f;
  for (int i = threadIdx.x; i < n; i += BLOCK) acc += partial[i];
  #pragma unroll
  for (int off = 32; off > 0; off >>= 1) acc += __shfl_down(acc, off, 64);

  __shared__ float smem[BLOCK / 64];
  const int lane = threadIdx.x & 63;
  const int wid  = threadIdx.x >> 6;
  if (lane == 0) smem[wid] = acc;
  __syncthreads();
  if (threadIdx.x == 0) {
    float s = 0.0f;
    #pragma unroll
    for (int k = 0; k < BLOCK / 64; ++k) s += smem[k];
    out[0] = s;
  }
}

extern "C" void kernel_launch(void* const* d_in, const int* in_sizes, int n_in,
                              void* d_out, int out_size, void* d_ws, size_t ws_size,
                              hipStream_t stream) {
  const float* pred = (const float*)d_in[0];
  // d_in[1] (target, int32) is mathematically dead: one-hot masks sum to 1.
  const long long n = (long long)in_sizes[0];
  float* out = (float*)d_out;
  float* partial = (float*)d_ws;  // GRID1 floats, well within ws_size

  sum_stage1<<<GRID1, BLOCK, 0, stream>>>(pred, n, partial);
  sum_stage2<<<1, BLOCK, 0, stream>>>(partial, GRID1, out);
}